// Round 8
// baseline (217.702 us; speedup 1.0000x reference)
//
#include <hip/hip_runtime.h>
#include <hip/hip_cooperative_groups.h>
namespace cg = cooperative_groups;

constexpr int Bn = 2;
constexpr int Ln = 1024;
constexpr int Dn = 768;
constexpr int Hn = 128;
constexpr int KM1 = 63;
constexpr int Wn = 961;
constexpr int NROW = Bn * Wn;          // 1922
constexpr int GRID = 256;
constexpr int THR = 512;
constexpr float EPSf = 1e-8f;

// phase 1: block = 8-row group, full 128 h; 16 col-slices (interleaved by 4)
constexpr int RB1 = 8;
constexpr int PSTR = 132;              // padded part stride (128 h + 4)
// phase 2: unit = (b, 8-window chunk)
constexpr int WB2 = 8;
constexpr int CH2 = (Wn + WB2 - 1) / WB2;   // 121
constexpr int U2 = Bn * CH2;                // 242
// phase 3: unit = (b, 16-window chunk, 256-d chunk)
constexpr int WB3 = 16;
constexpr int CH3 = (Wn + WB3 - 1) / WB3;   // 61
constexpr int U3 = Bn * CH3 * 3;            // 366

constexpr int POOLF = RB1 * Dn + 4 * RB1 * PSTR;  // 6144 + 4224 = 10368 floats

__device__ __forceinline__ float4 f4l(const float* p) { return *reinterpret_cast<const float4*>(p); }
__device__ __forceinline__ void f4s(float* p, float4 v) { *reinterpret_cast<float4*>(p) = v; }
__device__ __forceinline__ float4 f4fma(float s, float4 w, float4 a) {
    a.x = fmaf(s, w.x, a.x); a.y = fmaf(s, w.y, a.y);
    a.z = fmaf(s, w.z, a.z); a.w = fmaf(s, w.w, a.w);
    return a;
}

// ===========================================================================
// Phase 1: xw1 = x @ w1[:D] (block = 8 rows, all 128 h); blocks 0..15 also
// fold pos_emb -> pew1 (+b1). Head rows copied to out.
// ===========================================================================
__device__ void phase1(float* xs, float* part,
                       const float* __restrict__ x, const float* __restrict__ pos_emb,
                       const float* __restrict__ w1, const float* __restrict__ b1,
                       float* __restrict__ xw1, float* __restrict__ pew1,
                       float* __restrict__ out, int blk, int tid)
{
    const int r0 = blk * RB1;
    for (int idx = tid; idx < RB1 * (Dn / 4); idx += THR)
        ((float4*)xs)[idx] = ((const float4*)(x + r0 * Dn))[idx];
    __syncthreads();

    if ((blk & 127) < 8) {           // head rows (t < 63) pass through
        for (int idx = tid; idx < RB1 * (Dn / 4); idx += THR) {
            const int i = idx / (Dn / 4);
            const int r = r0 + i;
            if ((r & (Ln - 1)) < KM1)
                ((float4*)out)[r * (Dn / 4) + idx - i * (Dn / 4)] = ((const float4*)xs)[idx];
        }
    }

    const int hh = tid >> 8;         // h-half
    const int t = tid & 255;
    const int h4 = t & 15;
    const int s = (t >> 4) & 15;     // col-slice, cols 4*s + 64*j
    const int quad = t >> 6;         // 0..3
    const int hbase = hh * 64 + 4 * h4;

    float4 acc[RB1];
    #pragma unroll
    for (int r = 0; r < RB1; ++r) acc[r] = make_float4(0.f, 0.f, 0.f, 0.f);
    #pragma unroll
    for (int j = 0; j < 12; ++j) {
        const int c = 4 * s + 64 * j;
        const float* wp = w1 + c * Hn + hbase;
        const float4 wv0 = f4l(wp);
        const float4 wv1 = f4l(wp + Hn);
        const float4 wv2 = f4l(wp + 2 * Hn);
        const float4 wv3 = f4l(wp + 3 * Hn);
        #pragma unroll
        for (int r = 0; r < RB1; ++r) {
            const float4 xv = ((const float4*)xs)[r * (Dn / 4) + s + 16 * j];
            acc[r] = f4fma(xv.x, wv0, acc[r]);
            acc[r] = f4fma(xv.y, wv1, acc[r]);
            acc[r] = f4fma(xv.z, wv2, acc[r]);
            acc[r] = f4fma(xv.w, wv3, acc[r]);
        }
    }
    #pragma unroll
    for (int r = 0; r < RB1; ++r) {     // in-wave reduce over 4 slices
        acc[r].x += __shfl_xor(acc[r].x, 16); acc[r].y += __shfl_xor(acc[r].y, 16);
        acc[r].z += __shfl_xor(acc[r].z, 16); acc[r].w += __shfl_xor(acc[r].w, 16);
        acc[r].x += __shfl_xor(acc[r].x, 32); acc[r].y += __shfl_xor(acc[r].y, 32);
        acc[r].z += __shfl_xor(acc[r].z, 32); acc[r].w += __shfl_xor(acc[r].w, 32);
    }
    if ((t & 48) == 0) {
        #pragma unroll
        for (int r = 0; r < RB1; ++r)
            f4s(part + (quad * RB1 + r) * PSTR + hbase, acc[r]);
    }
    __syncthreads();
    for (int o = tid; o < RB1 * Hn; o += THR) {
        const int r = o >> 7, hl = o & 127;
        float sum = 0.f;
        #pragma unroll
        for (int q = 0; q < 4; ++q) sum += part[(q * RB1 + r) * PSTR + hl];
        xw1[(r0 + r) * Hn + hl] = sum;
    }

    if (blk < 16) {                   // pos_emb rows, 4 per block
        const int pr0 = blk * 4;
        const int nv = min(4, KM1 - pr0);
        __syncthreads();              // xs & part readers all done above
        for (int idx = tid; idx < nv * (Dn / 4); idx += THR)
            ((float4*)xs)[idx] = ((const float4*)(pos_emb + pr0 * Dn))[idx];
        __syncthreads();
        float4 pa[4];
        #pragma unroll
        for (int r = 0; r < 4; ++r) pa[r] = make_float4(0.f, 0.f, 0.f, 0.f);
        #pragma unroll
        for (int j = 0; j < 12; ++j) {
            const int c = 4 * s + 64 * j;
            const float* wp = w1 + (Dn + c) * Hn + hbase;
            const float4 wv0 = f4l(wp);
            const float4 wv1 = f4l(wp + Hn);
            const float4 wv2 = f4l(wp + 2 * Hn);
            const float4 wv3 = f4l(wp + 3 * Hn);
            #pragma unroll
            for (int r = 0; r < 4; ++r) {
                const float4 xv = ((const float4*)xs)[r * (Dn / 4) + s + 16 * j];
                pa[r] = f4fma(xv.x, wv0, pa[r]);
                pa[r] = f4fma(xv.y, wv1, pa[r]);
                pa[r] = f4fma(xv.z, wv2, pa[r]);
                pa[r] = f4fma(xv.w, wv3, pa[r]);
            }
        }
        #pragma unroll
        for (int r = 0; r < 4; ++r) {
            pa[r].x += __shfl_xor(pa[r].x, 16); pa[r].y += __shfl_xor(pa[r].y, 16);
            pa[r].z += __shfl_xor(pa[r].z, 16); pa[r].w += __shfl_xor(pa[r].w, 16);
            pa[r].x += __shfl_xor(pa[r].x, 32); pa[r].y += __shfl_xor(pa[r].y, 32);
            pa[r].z += __shfl_xor(pa[r].z, 32); pa[r].w += __shfl_xor(pa[r].w, 32);
        }
        if ((t & 48) == 0) {
            #pragma unroll
            for (int r = 0; r < 4; ++r)
                f4s(part + (quad * RB1 + r) * PSTR + hbase, pa[r]);
        }
        __syncthreads();
        {
            const int r = tid >> 7, hl = tid & 127;   // 512 threads exactly
            if (r < nv) {
                float sum = 0.f;
                #pragma unroll
                for (int q = 0; q < 4; ++q) sum += part[(q * RB1 + r) * PSTR + hl];
                pew1[(pr0 + r) * Hn + hl] = sum + b1[hl];
            }
        }
    }
}

// ===========================================================================
// Phase 2: hbar[b,w,:] = mean_k relu(xw1[b,w+k,:] + pew1[k,:])
// ===========================================================================
__device__ void phase2(float* kred, const float* __restrict__ xw1,
                       const float* __restrict__ pew1, float* __restrict__ hbar,
                       int u, int tid)
{
    const int b = u / CH2;
    const int chunk = u % CH2;
    const int w0 = chunk * WB2;
    const int wcount = min(WB2, Wn - w0);
    const int h4 = tid & 31;
    const int kg = tid >> 5;              // 0..15
    float4 sw[WB2];
    #pragma unroll
    for (int w = 0; w < WB2; ++w) sw[w] = make_float4(0.f, 0.f, 0.f, 0.f);
    for (int k = kg; k < KM1; k += 16) {
        const float4 pv = f4l(pew1 + k * Hn + 4 * h4);
        #pragma unroll
        for (int w = 0; w < WB2; ++w) {
            int rr = w0 + w + k; rr = rr < Ln ? rr : (Ln - 1);   // clamp junk lanes
            const float4 xv = f4l(xw1 + (b * Ln + rr) * Hn + 4 * h4);
            sw[w].x += fmaxf(xv.x + pv.x, 0.f);
            sw[w].y += fmaxf(xv.y + pv.y, 0.f);
            sw[w].z += fmaxf(xv.z + pv.z, 0.f);
            sw[w].w += fmaxf(xv.w + pv.w, 0.f);
        }
    }
    #pragma unroll
    for (int w = 0; w < WB2; ++w) {       // in-wave: combine kg pairs (xor 32)
        sw[w].x += __shfl_xor(sw[w].x, 32);
        sw[w].y += __shfl_xor(sw[w].y, 32);
        sw[w].z += __shfl_xor(sw[w].z, 32);
        sw[w].w += __shfl_xor(sw[w].w, 32);
    }
    const int kgE = tid >> 6;             // 0..7
    if ((tid & 63) < 32) {
        #pragma unroll
        for (int w = 0; w < WB2; ++w)
            ((float4*)kred)[(kgE * WB2 + w) * 32 + h4] = sw[w];
    }
    __syncthreads();
    const float scl = 1.0f / 63.0f;
    for (int o = tid; o < WB2 * Hn; o += THR) {
        const int w = o >> 7, h = o & 127;
        if (w < wcount) {
            float tsum = 0.f;
            #pragma unroll
            for (int g = 0; g < 8; ++g)
                tsum += kred[(g * WB2 + w) * 128 + h];
            hbar[(b * Wn + w0 + w) * Hn + h] = tsum * scl;
        }
    }
}

// ===========================================================================
// Phase 3: pred = hbar @ w2 + b2 ; update/out ; single-writer row partials.
// ===========================================================================
__device__ void phase3(float* hsm, const float* __restrict__ x,
                       const float* __restrict__ alpha_p, const float* __restrict__ w2,
                       const float* __restrict__ b2, const float* __restrict__ hbar,
                       float* __restrict__ out, float* __restrict__ partial,
                       int u, int tid)
{
    const int dc = u % 3;
    const int rest = u / 3;
    const int b = rest / CH3;
    const int chunk = rest % CH3;
    const int w0 = chunk * WB3;
    const int wcount = min(WB3, Wn - w0);
    const float alpha = alpha_p[0];

    __syncthreads();                      // hsm safe to overwrite
    {
        const int idx = tid;              // WB3*Hn/4 = 512 exactly
        const int w = idx >> 5;
        ((float4*)hsm)[idx] = (w < wcount)
            ? ((const float4*)(hbar + (b * Wn + w0) * Hn))[idx]
            : make_float4(0.f, 0.f, 0.f, 0.f);
    }
    __syncthreads();

    const int wg = tid >> 6;              // 8 waves, 2 windows each
    const int d4 = tid & 63;
    const int d = dc * 256 + d4 * 4;
    const int w0r = (wg * 2) * 32, w1r = (wg * 2 + 1) * 32;
    float4 acc0 = make_float4(0.f, 0.f, 0.f, 0.f);
    float4 acc1 = acc0;
    for (int hi = 0; hi < 32; ++hi) {
        const float* wp = w2 + (4 * hi) * Dn + d;
        const float4 wv0 = f4l(wp);
        const float4 wv1 = f4l(wp + Dn);
        const float4 wv2 = f4l(wp + 2 * Dn);
        const float4 wv3 = f4l(wp + 3 * Dn);
        const float4 h0 = ((const float4*)hsm)[w0r + hi];
        const float4 h1 = ((const float4*)hsm)[w1r + hi];
        acc0 = f4fma(h0.x, wv0, acc0); acc0 = f4fma(h0.y, wv1, acc0);
        acc0 = f4fma(h0.z, wv2, acc0); acc0 = f4fma(h0.w, wv3, acc0);
        acc1 = f4fma(h1.x, wv0, acc1); acc1 = f4fma(h1.y, wv1, acc1);
        acc1 = f4fma(h1.z, wv2, acc1); acc1 = f4fma(h1.w, wv3, acc1);
    }
    const float4 bb = f4l(b2 + d);
    #pragma unroll
    for (int j = 0; j < 2; ++j) {
        const int w = wg * 2 + j;
        float4 pp = make_float4(0.f, 0.f, 0.f, 0.f);
        if (w < wcount) {
            const float4 sum0 = (j == 0) ? acc0 : acc1;
            const int row = b * Ln + w0 + w + KM1;
            const int off = row * Dn + d;
            const float4 xv = f4l(x + off);
            float4 md;
            md.x = xv.x - (sum0.x + bb.x);
            md.y = xv.y - (sum0.y + bb.y);
            md.z = xv.z - (sum0.z + bb.z);
            md.w = xv.w - (sum0.w + bb.w);
            float4 nb;
            nb.x = fmaf(-alpha, md.x, xv.x);
            nb.y = fmaf(-alpha, md.y, xv.y);
            nb.z = fmaf(-alpha, md.z, xv.z);
            nb.w = fmaf(-alpha, md.w, xv.w);
            f4s(out + off, nb);
            pp.x = md.x * md.x + md.y * md.y + md.z * md.z + md.w * md.w;
            pp.y = xv.x * xv.x + xv.y * xv.y + xv.z * xv.z + xv.w * xv.w;
            pp.z = xv.x * nb.x + xv.y * nb.y + xv.z * nb.z + xv.w * nb.w;
            pp.w = nb.x * nb.x + nb.y * nb.y + nb.z * nb.z + nb.w * nb.w;
        }
        #pragma unroll
        for (int o = 32; o > 0; o >>= 1) {
            pp.x += __shfl_xor(pp.x, o);
            pp.y += __shfl_xor(pp.y, o);
            pp.z += __shfl_xor(pp.z, o);
            pp.w += __shfl_xor(pp.w, o);
        }
        if ((tid & 63) == 0 && w < wcount)
            f4s(partial + (dc * NROW + b * Wn + w0 + w) * 4, pp);
    }
}

// ===========================================================================
// Phase 4: reduce 3x1922 partials -> 4 scalars.
// ===========================================================================
__device__ void phase4(float* fin, const float* __restrict__ partial,
                       const float* __restrict__ alpha_p, float* __restrict__ out,
                       int tid)
{
    const float alpha = alpha_p[0];
    float se = 0.f, sn = 0.f, sc = 0.f;
    const float4* pf = (const float4*)partial;
    for (int r = tid; r < NROW; r += THR) {
        const float4 v0 = pf[r];
        const float4 v1 = pf[NROW + r];
        const float4 v2 = pf[2 * NROW + r];
        const float sq = v0.x + v1.x + v2.x;
        const float aa = v0.y + v1.y + v2.y;
        const float ab = v0.z + v1.z + v2.z;
        const float bbs = v0.w + v1.w + v2.w;
        se += sq;
        sn += sqrtf(sq);
        sc += ab / (fmaxf(sqrtf(aa), EPSf) * fmaxf(sqrtf(bbs), EPSf));
    }
    #pragma unroll
    for (int o = 32; o > 0; o >>= 1) {
        se += __shfl_down(se, o);
        sn += __shfl_down(sn, o);
        sc += __shfl_down(sc, o);
    }
    const int wv = tid >> 6, lane = tid & 63;
    if (lane == 0) { fin[wv * 3 + 0] = se; fin[wv * 3 + 1] = sn; fin[wv * 3 + 2] = sc; }
    __syncthreads();
    if (tid == 0) {
        float te = 0.f, tn = 0.f, tc = 0.f;
        #pragma unroll
        for (int i = 0; i < 8; ++i) {
            te += fin[i * 3 + 0]; tn += fin[i * 3 + 1]; tc += fin[i * 3 + 2];
        }
        const float inv = 1.0f / (float)NROW;
        const float pre = te * inv;
        const float om = 1.0f - alpha;
        const int base = Bn * Ln * Dn;
        out[base + 0] = pre;
        out[base + 1] = om * om * pre;
        out[base + 2] = alpha * tn * inv;
        out[base + 3] = tc * inv;
    }
}

// ===========================================================================
// Cooperative single-kernel path.
// ===========================================================================
__global__ __launch_bounds__(THR)
void k_all(const float* __restrict__ x, const float* __restrict__ alpha_p,
           const float* __restrict__ pos_emb, const float* __restrict__ w1,
           const float* __restrict__ b1, const float* __restrict__ w2,
           const float* __restrict__ b2, float* __restrict__ out,
           float* __restrict__ xw1, float* __restrict__ pew1,
           float* __restrict__ hbar, float* __restrict__ partial)
{
    __shared__ __align__(16) float pool[POOLF];   // 41.5 KB
    cg::grid_group grid = cg::this_grid();
    const int blk = blockIdx.x;
    const int tid = threadIdx.x;

    phase1(pool, pool + RB1 * Dn, x, pos_emb, w1, b1, xw1, pew1, out, blk, tid);
    grid.sync();
    if (blk < U2) phase2(pool, xw1, pew1, hbar, blk, tid);
    grid.sync();
    phase3(pool, x, alpha_p, w2, b2, hbar, out, partial, blk, tid);
    if (blk + GRID < U3)
        phase3(pool, x, alpha_p, w2, b2, hbar, out, partial, blk + GRID, tid);
    grid.sync();
    if (blk == 0) phase4(pool, partial, alpha_p, out, tid);
}

// ===========================================================================
// Fallback: same phases as 4 regular kernels.
// ===========================================================================
__global__ __launch_bounds__(THR)
void k_p1(const float* x, const float* pos_emb, const float* w1, const float* b1,
          float* xw1, float* pew1, float* out)
{
    __shared__ __align__(16) float pool[POOLF];
    phase1(pool, pool + RB1 * Dn, x, pos_emb, w1, b1, xw1, pew1, out,
           blockIdx.x, threadIdx.x);
}
__global__ __launch_bounds__(THR)
void k_p2(const float* xw1, const float* pew1, float* hbar)
{
    __shared__ __align__(16) float pool[8192];
    phase2(pool, xw1, pew1, hbar, blockIdx.x, threadIdx.x);
}
__global__ __launch_bounds__(THR)
void k_p3(const float* x, const float* alpha_p, const float* w2, const float* b2,
          const float* hbar, float* out, float* partial)
{
    __shared__ __align__(16) float pool[2048];
    phase3(pool, x, alpha_p, w2, b2, hbar, out, partial, blockIdx.x, threadIdx.x);
}
__global__ __launch_bounds__(THR)
void k_p4(const float* partial, const float* alpha_p, float* out)
{
    __shared__ __align__(16) float pool[32];
    phase4(pool, partial, alpha_p, out, threadIdx.x);
}

extern "C" void kernel_launch(void* const* d_in, const int* in_sizes, int n_in,
                              void* d_out, int out_size, void* d_ws, size_t ws_size,
                              hipStream_t stream)
{
    const float* x       = (const float*)d_in[0];
    const float* alpha_p = (const float*)d_in[1];
    const float* pos_emb = (const float*)d_in[2];
    const float* w1      = (const float*)d_in[3];
    const float* b1      = (const float*)d_in[4];
    const float* w2      = (const float*)d_in[5];
    const float* b2      = (const float*)d_in[6];
    float* out = (float*)d_out;

    // ws (floats): xw1 [2048*128] | pew1 [64*128] | hbar [1922*128] | partial [3*1922*4]
    float* xw1     = (float*)d_ws;
    float* pew1    = xw1 + Bn * Ln * Hn;
    float* hbar    = pew1 + 64 * Hn;
    float* partial = hbar + NROW * Hn;

    void* args[] = { (void*)&x, (void*)&alpha_p, (void*)&pos_emb, (void*)&w1,
                     (void*)&b1, (void*)&w2, (void*)&b2, (void*)&out,
                     (void*)&xw1, (void*)&pew1, (void*)&hbar, (void*)&partial };
    hipError_t err = hipLaunchCooperativeKernel((const void*)k_all, dim3(GRID),
                                                dim3(THR), args, 0, stream);
    if (err != hipSuccess) {   // deterministic fallback: 4 regular dispatches
        k_p1<<<GRID, THR, 0, stream>>>(x, pos_emb, w1, b1, xw1, pew1, out);
        k_p2<<<U2, THR, 0, stream>>>(xw1, pew1, hbar);
        k_p3<<<U3, THR, 0, stream>>>(x, alpha_p, w2, b2, hbar, out, partial);
        k_p4<<<1, THR, 0, stream>>>(partial, alpha_p, out);
    }
}

// Round 9
// 116.406 us; speedup vs baseline: 1.8702x; 1.8702x over previous
//
#include <hip/hip_runtime.h>

constexpr int Bn = 2;
constexpr int Ln = 1024;
constexpr int Dn = 768;
constexpr int Hn = 128;          // MLP_HIDDEN
constexpr int KM1 = 63;          // K-1
constexpr int Wn = 961;          // windows
constexpr int NROW = Bn * Wn;    // 1922
constexpr float EPSf = 1e-8f;

// gemm1 geometry: block = (16-row group) x (h-half of 64 cols)
constexpr int RB1 = 16;
constexpr int NXG = (Bn * Ln) / RB1;     // 128 x-row groups
constexpr int NPG = 4;                   // pos_emb groups (63 rows)
constexpr int G1 = (NXG + NPG) * 2;      // 264 blocks
constexpr int PSTR = 68;                 // padded part stride

// fused geometry: block = (b, 8-window chunk, 256-d chunk)  [R4-proven]
constexpr int WB = 8;
constexpr int WCH = (Wn + WB - 1) / WB;  // 121
constexpr int FG = Bn * WCH * 3;         // 726 blocks

__device__ __forceinline__ float4 f4l(const float* p) { return *reinterpret_cast<const float4*>(p); }
__device__ __forceinline__ void f4s(float* p, float4 v) { *reinterpret_cast<float4*>(p) = v; }
__device__ __forceinline__ float4 f4fma(float s, float4 w, float4 a) {
    a.x = fmaf(s, w.x, a.x); a.y = fmaf(s, w.y, a.y);
    a.z = fmaf(s, w.z, a.z); a.w = fmaf(s, w.w, a.w);
    return a;
}

// ---------------------------------------------------------------------------
// Kernel A: xw1 = x @ w1[:D] ; pew1 = pos_emb @ w1[D:] + b1 ; head-row copy.
// 264 blocks x 512 thr. Thread = h4(16) x ks(32 slices of 24 cols), each
// thread accumulates ALL 16 rows -> each w1 element read once per block.
// Wave folds its 4 ks-slices via shuffle; 8 quads reduced through LDS
// (part aliases xs after all xs reads complete).
// ---------------------------------------------------------------------------
__global__ __launch_bounds__(512)
void k_gemm1(const float* __restrict__ x, const float* __restrict__ pos_emb,
             const float* __restrict__ w1, const float* __restrict__ b1,
             float* __restrict__ xw1, float* __restrict__ pew1,
             float* __restrict__ out)
{
    __shared__ __align__(16) float pool[RB1 * Dn];   // 48 KB (xs, then part)
    float* xs = pool;
    float* part = pool;                               // aliased after sync

    const int tid = threadIdx.x;
    const int blk = blockIdx.x;
    const bool isX = blk < 2 * NXG;
    const int sub = isX ? blk : (blk - 2 * NXG);
    const int grp = sub >> 1;
    const int hh = sub & 1;
    const int r0 = grp * RB1;

    const float* src = isX ? (x + r0 * Dn) : (pos_emb + r0 * Dn);
    const int nv = isX ? RB1 : min(RB1, KM1 - r0);

    for (int idx = tid; idx < nv * (Dn / 4); idx += 512)
        ((float4*)xs)[idx] = ((const float4*)src)[idx];
    __syncthreads();

    // head rows (t < K-1) pass through unchanged (hh==0 x-blocks only)
    if (isX && hh == 0 && (grp & (Ln / RB1 - 1)) < 4) {
        for (int idx = tid; idx < RB1 * (Dn / 4); idx += 512) {
            const int i = idx / (Dn / 4);
            const int r = r0 + i;
            if ((r & (Ln - 1)) < KM1)
                ((float4*)out)[r * (Dn / 4) + idx - i * (Dn / 4)] = ((const float4*)xs)[idx];
        }
    }

    const int h4 = tid & 15;                 // h-col group within half
    const int ks = tid >> 4;                 // 0..31, 24-col slice
    const int hbase = hh * 64 + 4 * h4;      // global h
    const int woff = isX ? 0 : Dn;

    float4 acc[RB1];
    #pragma unroll
    for (int r = 0; r < RB1; ++r) acc[r] = make_float4(0.f, 0.f, 0.f, 0.f);

    const int c0 = ks * 24;
    #pragma unroll
    for (int cc = 0; cc < 24; cc += 4) {
        const int c = c0 + cc;
        const float* wp = w1 + (woff + c) * Hn + hbase;
        const float4 wv0 = f4l(wp);
        const float4 wv1 = f4l(wp + Hn);
        const float4 wv2 = f4l(wp + 2 * Hn);
        const float4 wv3 = f4l(wp + 3 * Hn);
        #pragma unroll
        for (int r = 0; r < RB1; ++r) {
            const float4 xv = ((const float4*)xs)[r * (Dn / 4) + (c >> 2)];
            acc[r] = f4fma(xv.x, wv0, acc[r]);
            acc[r] = f4fma(xv.y, wv1, acc[r]);
            acc[r] = f4fma(xv.z, wv2, acc[r]);
            acc[r] = f4fma(xv.w, wv3, acc[r]);
        }
    }

    // fold the 4 ks-slices sharing each wave (lanes xor 16, 32)
    #pragma unroll
    for (int r = 0; r < RB1; ++r) {
        acc[r].x += __shfl_xor(acc[r].x, 16); acc[r].y += __shfl_xor(acc[r].y, 16);
        acc[r].z += __shfl_xor(acc[r].z, 16); acc[r].w += __shfl_xor(acc[r].w, 16);
        acc[r].x += __shfl_xor(acc[r].x, 32); acc[r].y += __shfl_xor(acc[r].y, 32);
        acc[r].z += __shfl_xor(acc[r].z, 32); acc[r].w += __shfl_xor(acc[r].w, 32);
    }
    __syncthreads();                         // all xs reads done -> reuse as part

    const int q = tid >> 6;                  // wave id 0..7
    if ((tid & 48) == 0) {
        #pragma unroll
        for (int r = 0; r < RB1; ++r)
            f4s(part + (q * RB1 + r) * PSTR + 4 * h4, acc[r]);
    }
    __syncthreads();

    for (int o = tid; o < RB1 * 64; o += 512) {
        const int r = o >> 6, hl = o & 63;
        float s = 0.f;
        #pragma unroll
        for (int k2 = 0; k2 < 8; ++k2)
            s += part[(k2 * RB1 + r) * PSTR + hl];
        if (isX) {
            xw1[(r0 + r) * Hn + hh * 64 + hl] = s;
        } else if (r < nv) {
            pew1[(r0 + r) * Hn + hh * 64 + hl] = s + b1[hh * 64 + hl];
        }
    }
}

// ---------------------------------------------------------------------------
// Kernel B (fused, R4-proven): per (b, 8-window chunk, 256-d chunk):
//   stage xw1 slab [<=70][128] -> LDS; hbar[8][128] locally;
//   pred = hbar @ w2 + b2 ; update/out ; row partials -> partial[dc][row].
// 726 blocks x 256 thr, 71 KB LDS.
// ---------------------------------------------------------------------------
__global__ __launch_bounds__(256)
void k_fused(const float* __restrict__ x, const float* __restrict__ alpha_p,
             const float* __restrict__ w2, const float* __restrict__ b2,
             const float* __restrict__ xw1, const float* __restrict__ pew1,
             float* __restrict__ out, float* __restrict__ partial)
{
    __shared__ float xsl[(WB + KM1 - 1) * Hn];  // 70*128 = 35 KB
    __shared__ float hsm[WB * Hn];              // 4 KB
    __shared__ float4 red[4 * WB * 64];         // 32 KB
    const int tid = threadIdx.x;
    int bid = blockIdx.x;
    const int dc = bid % 3; bid /= 3;
    const int chunk = bid % WCH;
    const int b = bid / WCH;
    const int w0 = chunk * WB;
    const int wcount = min(WB, Wn - w0);
    const int nrows = wcount + KM1 - 1;         // <= 70
    const float alpha = alpha_p[0];

    // stage xw1 slab
    {
        const float4* src = (const float4*)(xw1 + (b * Ln + w0) * Hn);
        for (int idx = tid; idx < nrows * (Hn / 4); idx += 256)
            ((float4*)xsl)[idx] = src[idx];
    }
    __syncthreads();

    // hbar: kg(8) x h4(32); pew1 prefetched x8
    {
        const int kg = tid >> 5;
        const int h4 = tid & 31;
        float4 pv[8];
        #pragma unroll
        for (int j = 0; j < 8; ++j)              // row 63 in-bounds (64-row buf), unused
            pv[j] = f4l(pew1 + (kg * 8 + j) * Hn + 4 * h4);
        const int nj = (kg == 7) ? 7 : 8;
        float4 s[WB];
        #pragma unroll
        for (int w = 0; w < WB; ++w) s[w] = make_float4(0.f, 0.f, 0.f, 0.f);
        for (int j = 0; j < nj; ++j) {
            const int k = kg * 8 + j;
            #pragma unroll
            for (int w = 0; w < WB; ++w) {
                const float4 xv = ((const float4*)xsl)[(w + k) * (Hn / 4) + h4];
                s[w].x += fmaxf(xv.x + pv[j].x, 0.f);
                s[w].y += fmaxf(xv.y + pv[j].y, 0.f);
                s[w].z += fmaxf(xv.z + pv[j].z, 0.f);
                s[w].w += fmaxf(xv.w + pv[j].w, 0.f);
            }
        }
        #pragma unroll
        for (int w = 0; w < WB; ++w)
            red[(kg * WB + w) * 32 + h4] = s[w];
    }
    __syncthreads();
    {   // reduce 8 kg
        const int w = tid >> 5;
        const int h4 = tid & 31;
        float4 t = red[w * 32 + h4];
        #pragma unroll
        for (int kg = 1; kg < 8; ++kg) {
            const float4 u = red[(kg * WB + w) * 32 + h4];
            t.x += u.x; t.y += u.y; t.z += u.z; t.w += u.w;
        }
        const float sc = 1.0f / 63.0f;
        t.x *= sc; t.y *= sc; t.z *= sc; t.w *= sc;
        ((float4*)hsm)[w * 32 + h4] = t;
    }
    __syncthreads();

    // GEMM2 (this dc slice): hs(4) x d4(64); w2 loads batched x4
    const int d4 = tid & 63;
    const int hs = tid >> 6;
    float4 acc[WB];
    #pragma unroll
    for (int w = 0; w < WB; ++w) acc[w] = make_float4(0.f, 0.f, 0.f, 0.f);
    {
        const float* wbase = w2 + (hs * 32) * Dn + dc * 256 + d4 * 4;
        #pragma unroll
        for (int t = 0; t < 8; ++t) {
            const float4 wv0 = f4l(wbase + (4 * t + 0) * Dn);
            const float4 wv1 = f4l(wbase + (4 * t + 1) * Dn);
            const float4 wv2 = f4l(wbase + (4 * t + 2) * Dn);
            const float4 wv3 = f4l(wbase + (4 * t + 3) * Dn);
            const int h = hs * 32 + 4 * t;
            #pragma unroll
            for (int w = 0; w < WB; ++w) {
                acc[w] = f4fma(hsm[w * Hn + h + 0], wv0, acc[w]);
                acc[w] = f4fma(hsm[w * Hn + h + 1], wv1, acc[w]);
                acc[w] = f4fma(hsm[w * Hn + h + 2], wv2, acc[w]);
                acc[w] = f4fma(hsm[w * Hn + h + 3], wv3, acc[w]);
            }
        }
    }
    #pragma unroll
    for (int w = 0; w < WB; ++w)
        red[(hs * WB + w) * 64 + d4] = acc[w];
    __syncthreads();

    // combine h-splits, update/out, row partials (single writer per slot)
    const int wloc = tid >> 5;                   // 8 windows x 32 threads
    float4 pp = make_float4(0.f, 0.f, 0.f, 0.f);
    if (wloc < wcount) {
        const int rowoff = (b * Ln + w0 + wloc + KM1) * Dn + dc * 256;
        #pragma unroll
        for (int j = 0; j < 2; ++j) {
            const int dp = (2 * tid + j) & 63;
            float4 sum = red[wloc * 64 + dp];
            #pragma unroll
            for (int k = 1; k < 4; ++k) {
                const float4 u = red[(k * WB + wloc) * 64 + dp];
                sum.x += u.x; sum.y += u.y; sum.z += u.z; sum.w += u.w;
            }
            const float4 bb = f4l(b2 + dc * 256 + dp * 4);
            const float4 xv = f4l(x + rowoff + dp * 4);
            float4 md;
            md.x = xv.x - (sum.x + bb.x);
            md.y = xv.y - (sum.y + bb.y);
            md.z = xv.z - (sum.z + bb.z);
            md.w = xv.w - (sum.w + bb.w);
            float4 nb;
            nb.x = fmaf(-alpha, md.x, xv.x);
            nb.y = fmaf(-alpha, md.y, xv.y);
            nb.z = fmaf(-alpha, md.z, xv.z);
            nb.w = fmaf(-alpha, md.w, xv.w);
            f4s(out + rowoff + dp * 4, nb);
            pp.x += md.x * md.x + md.y * md.y + md.z * md.z + md.w * md.w;
            pp.y += xv.x * xv.x + xv.y * xv.y + xv.z * xv.z + xv.w * xv.w;
            pp.z += xv.x * nb.x + xv.y * nb.y + xv.z * nb.z + xv.w * nb.w;
            pp.w += nb.x * nb.x + nb.y * nb.y + nb.z * nb.z + nb.w * nb.w;
        }
        #pragma unroll
        for (int off = 16; off > 0; off >>= 1) {
            pp.x += __shfl_xor(pp.x, off);
            pp.y += __shfl_xor(pp.y, off);
            pp.z += __shfl_xor(pp.z, off);
            pp.w += __shfl_xor(pp.w, off);
        }
        if ((tid & 31) == 0)
            f4s(partial + (dc * NROW + b * Wn + w0 + wloc) * 4, pp);
    }
}

// ---------------------------------------------------------------------------
// Kernel C: sum 3 d-chunk partials per row -> 4 scalars.
// ---------------------------------------------------------------------------
__global__ __launch_bounds__(1024)
void k_final(const float* __restrict__ partial, const float* __restrict__ alpha_p,
             float* __restrict__ out)
{
    __shared__ float sred[16][3];
    const int tid = threadIdx.x;
    float se = 0.f, sn = 0.f, sc = 0.f;
    for (int r = tid; r < NROW; r += 1024) {
        const float4 v0 = ((const float4*)partial)[r];
        const float4 v1 = ((const float4*)partial)[NROW + r];
        const float4 v2 = ((const float4*)partial)[2 * NROW + r];
        const float sq = v0.x + v1.x + v2.x;
        const float aa = v0.y + v1.y + v2.y;
        const float ab = v0.z + v1.z + v2.z;
        const float bb = v0.w + v1.w + v2.w;
        se += sq;
        sn += sqrtf(sq);
        sc += ab / (fmaxf(sqrtf(aa), EPSf) * fmaxf(sqrtf(bb), EPSf));
    }
    #pragma unroll
    for (int off = 32; off > 0; off >>= 1) {
        se += __shfl_down(se, off);
        sn += __shfl_down(sn, off);
        sc += __shfl_down(sc, off);
    }
    const int wv = tid >> 6, lane = tid & 63;
    if (lane == 0) { sred[wv][0] = se; sred[wv][1] = sn; sred[wv][2] = sc; }
    __syncthreads();
    if (tid == 0) {
        float te = 0.f, tn = 0.f, tc = 0.f;
        #pragma unroll
        for (int i = 0; i < 16; ++i) {
            te += sred[i][0]; tn += sred[i][1]; tc += sred[i][2];
        }
        const float alpha = alpha_p[0];
        const float inv = 1.0f / (float)NROW;
        const float pre = te * inv;
        const float om = 1.0f - alpha;
        const int base = Bn * Ln * Dn;
        out[base + 0] = pre;
        out[base + 1] = om * om * pre;
        out[base + 2] = alpha * tn * inv;
        out[base + 3] = tc * inv;
    }
}

extern "C" void kernel_launch(void* const* d_in, const int* in_sizes, int n_in,
                              void* d_out, int out_size, void* d_ws, size_t ws_size,
                              hipStream_t stream)
{
    const float* x       = (const float*)d_in[0];
    const float* alpha_p = (const float*)d_in[1];
    const float* pos_emb = (const float*)d_in[2];
    const float* w1      = (const float*)d_in[3];
    const float* b1      = (const float*)d_in[4];
    const float* w2      = (const float*)d_in[5];
    const float* b2      = (const float*)d_in[6];
    float* out = (float*)d_out;

    // ws (floats): xw1 [2048*128] | pew1 [64*128] | partial [3*1922*4]
    float* xw1     = (float*)d_ws;
    float* pew1    = xw1 + Bn * Ln * Hn;
    float* partial = pew1 + 64 * Hn;

    k_gemm1<<<G1, 512, 0, stream>>>(x, pos_emb, w1, b1, xw1, pew1, out);
    k_fused<<<FG, 256, 0, stream>>>(x, alpha_p, w2, b2, xw1, pew1, out, partial);
    k_final<<<1, 1024, 0, stream>>>(partial, alpha_p, out);
}